// Round 4
// baseline (251.055 us; speedup 1.0000x reference)
//
#include <hip/hip_runtime.h>
#include <hip/hip_bf16.h>

// Problem constants (fixed by setup_inputs)
#define N_NODES   100000
#define MAX_DEG   64
#define NODE_DIM  256
#define NUM_V     8192
#define NSAMP     16
#define GROUP_DIM 4
#define SENTINEL  (N_NODES - 1)
#define VPB       4   // v's per block (amortizes W reads 4x)

// Fused kernel: per block, compute l_v = f_{ids[v]} @ W + b for VPB v's
// (bit-identical to the R3 GEMM: strict k-ascending fp32 fma chain per
// output, bias added after the full sum), then run the R2/R3 sampler body
// per v. Kills the separate GEMM dispatch + l round-trip through global.
//
// Sampler phase is byte-identical logic to R3 (pinned for 3 rounds at
// 85 us / 257 MB L2-miss / 3.1 TB/s — LLC random-delivery bound).
__global__ __launch_bounds__(256) void sampler_fused_kernel(
    const int* __restrict__ ids,
    const int* __restrict__ adj,
    const float* __restrict__ features,
    const float* __restrict__ W,
    const float* __restrict__ bias,
    float* __restrict__ out_sel,
    float* __restrict__ out_att,
    float* __restrict__ out_nz1,
    float* __restrict__ out_nz2) {
  __shared__ float l_s[VPB][NODE_DIM];
  __shared__ int   adj_s[MAX_DEG];
  __shared__ float nz_s[NSAMP];

  const int tid = threadIdx.x;
  const int v0  = blockIdx.x * VPB;

  // nids are wave-uniform scalar loads
  const int nid0 = ids[v0 + 0];
  const int nid1 = ids[v0 + 1];
  const int nid2 = ids[v0 + 2];
  const int nid3 = ids[v0 + 3];

  // ---- l computation: thread d = tid computes l[v0+i][d], i=0..3 ----
  // Strict k-ascending fmaf chain == R3 gemm contraction order (bit-exact).
  {
    const float* __restrict__ f0 = features + (size_t)nid0 * NODE_DIM;
    const float* __restrict__ f1 = features + (size_t)nid1 * NODE_DIM;
    const float* __restrict__ f2 = features + (size_t)nid2 * NODE_DIM;
    const float* __restrict__ f3 = features + (size_t)nid3 * NODE_DIM;

    float a0 = 0.0f, a1 = 0.0f, a2 = 0.0f, a3 = 0.0f;
#pragma unroll 8
    for (int k = 0; k < NODE_DIM; ++k) {
      const float wv = W[(size_t)k * NODE_DIM + tid];  // coalesced, L2-hot
      a0 = fmaf(f0[k], wv, a0);  // f*[k] wave-uniform -> scalar/broadcast
      a1 = fmaf(f1[k], wv, a1);
      a2 = fmaf(f2[k], wv, a2);
      a3 = fmaf(f3[k], wv, a3);
    }
    const float bv = bias[tid];
    l_s[0][tid] = a0 + bv;
    l_s[1][tid] = a1 + bv;
    l_s[2][tid] = a2 + bv;
    l_s[3][tid] = a3 + bv;
  }
  __syncthreads();

  // ---- sampler phase (R3 body), once per v ----
  const int wave = tid >> 6;       // 0..3
  const int lane = tid & 63;
  const int q    = lane >> 2;      // 0..15: neighbor slot within wave
  const int sub  = lane & 3;       // 0..3 : dim-chunk within quad
  const int kidx = wave * 16 + q;  // neighbor index 0..63

  const int nids[VPB] = {nid0, nid1, nid2, nid3};

  for (int i = 0; i < VPB; ++i) {
    const int v = v0 + i;

    if (tid < MAX_DEG) adj_s[tid] = adj[(size_t)nids[i] * MAX_DEG + tid];
    __syncthreads();

    const int nb = adj_s[kidx];
    const float* __restrict__ rowp =
        features + (size_t)nb * NODE_DIM + sub * 4;
    const float* __restrict__ lp = &l_s[i][sub * 4];

    float p = 0.0f;
#pragma unroll
    for (int c = 0; c < 16; ++c) {
      const float4 f  = *reinterpret_cast<const float4*>(rowp + c * 16);
      const float4 lv = *reinterpret_cast<const float4*>(lp + c * 16);
      p += f.x * lv.x + f.y * lv.y + f.z * lv.z + f.w * lv.w;
    }
    p += __shfl_xor(p, 1, 64);
    p += __shfl_xor(p, 2, 64);
    float s = p > 0.0f ? p : 0.0f;   // relu

    int g = q & 3;
    {
      float os = __shfl_xor(s, 4, 64);
      int   og = __shfl_xor(g, 4, 64);
      if (os < s || (os == s && og < g)) { s = os; g = og; }
      os = __shfl_xor(s, 8, 64);
      og = __shfl_xor(g, 8, 64);
      if (os < s || (os == s && og < g)) { s = os; g = og; }
    }

    if ((lane & 15) == 0) {
      const int gl    = lane >> 4;
      const int s_idx = wave * 4 + gl;
      const int selid = adj_s[s_idx * GROUP_DIM + g];
      out_sel[(size_t)v * NSAMP + s_idx] = (float)selid;
      out_att[(size_t)v * NSAMP + s_idx] = 1.0f;
      nz_s[s_idx] = (selid == SENTINEL) ? 0.0f : 1.0f;
    }
    __syncthreads();

    if (tid == 0) {
      float nz = 0.0f;
#pragma unroll
      for (int t = 0; t < NSAMP; ++t) nz += nz_s[t];
      out_nz1[v] = nz;
      out_nz2[v] = nz;
    }
    __syncthreads();  // protect adj_s / nz_s before next v
  }
}

extern "C" void kernel_launch(void* const* d_in, const int* in_sizes, int n_in,
                              void* d_out, int out_size, void* d_ws,
                              size_t ws_size, hipStream_t stream) {
  const int*   ids      = (const int*)d_in[0];
  const int*   adj      = (const int*)d_in[1];
  const float* features = (const float*)d_in[2];
  const float* W        = (const float*)d_in[3];
  const float* bias     = (const float*)d_in[4];

  float* out     = (float*)d_out;
  float* out_sel = out;
  float* out_att = out + (size_t)NUM_V * NSAMP;
  float* out_nz1 = out + (size_t)2 * NUM_V * NSAMP;
  float* out_nz2 = out_nz1 + NUM_V;

  sampler_fused_kernel<<<NUM_V / VPB, 256, 0, stream>>>(
      ids, adj, features, W, bias, out_sel, out_att, out_nz1, out_nz2);
}

// Round 5
// 236.217 us; speedup vs baseline: 1.0628x; 1.0628x over previous
//
#include <hip/hip_runtime.h>
#include <hip/hip_bf16.h>

// Problem constants (fixed by setup_inputs)
#define N_NODES   100000
#define MAX_DEG   64
#define NODE_DIM  256
#define NUM_V     8192
#define NSAMP     16
#define GROUP_DIM 4
#define SENTINEL  (N_NODES - 1)

// ---------------- Kernel 1: l = features[ids] @ W + b  ----------------
// C[8192x256] = gather(features, ids) @ W + b
// BM=64 x BN=64, BK=32, 256 threads, 4x4 acc/thread.
// Register-prefetch double buffer; As padded (stride 68) -> ds_write
// conflicts at 2-way (free on gfx950). Measured ~6 us (R3).
#define BM 64
#define BN 64
#define BK 32
#define AS_STRIDE (BM + 4)

__global__ __launch_bounds__(256) void gemm_l_kernel(
    const int* __restrict__ ids,
    const float* __restrict__ features,
    const float* __restrict__ W,
    const float* __restrict__ bias,
    float* __restrict__ l_out) {
  __shared__ float As[BK][AS_STRIDE];
  __shared__ float Ws[BK][BN];
  __shared__ int   nid_s[BM];

  const int tid  = threadIdx.x;
  const int row0 = blockIdx.x * BM;
  const int col0 = blockIdx.y * BN;

  if (tid < BM) nid_s[tid] = ids[row0 + tid];
  __syncthreads();

  const int tx = tid & 15;   // col group 0..15
  const int ty = tid >> 4;   // row group 0..15

  const int am = tid >> 2;          // 0..63
  const int ak = (tid & 3) * 4;     // 0,4,8,12
  const int wk = tid >> 4;          // 0..15
  const int wn = (tid & 15) * 4;    // 0..60

  const size_t a_base = (size_t)nid_s[am] * NODE_DIM + ak;
  const size_t w_base = (size_t)wk * NODE_DIM + col0 + wn;

  float4 av0, av1, wv0, wv1;
  av0 = *reinterpret_cast<const float4*>(&features[a_base]);
  av1 = *reinterpret_cast<const float4*>(&features[a_base + 16]);
  wv0 = *reinterpret_cast<const float4*>(&W[w_base]);
  wv1 = *reinterpret_cast<const float4*>(&W[w_base + 16 * NODE_DIM]);

  float acc[4][4] = {};

  for (int k0 = 0; k0 < NODE_DIM; k0 += BK) {
    As[ak + 0][am] = av0.x;
    As[ak + 1][am] = av0.y;
    As[ak + 2][am] = av0.z;
    As[ak + 3][am] = av0.w;
    As[ak + 16 + 0][am] = av1.x;
    As[ak + 16 + 1][am] = av1.y;
    As[ak + 16 + 2][am] = av1.z;
    As[ak + 16 + 3][am] = av1.w;
    *reinterpret_cast<float4*>(&Ws[wk][wn])      = wv0;
    *reinterpret_cast<float4*>(&Ws[wk + 16][wn]) = wv1;
    __syncthreads();

    if (k0 + BK < NODE_DIM) {
      const int kn = k0 + BK;
      av0 = *reinterpret_cast<const float4*>(&features[a_base + kn]);
      av1 = *reinterpret_cast<const float4*>(&features[a_base + kn + 16]);
      wv0 = *reinterpret_cast<const float4*>(&W[w_base + (size_t)kn * NODE_DIM]);
      wv1 = *reinterpret_cast<const float4*>(
          &W[w_base + (size_t)(kn + 16) * NODE_DIM]);
    }

#pragma unroll
    for (int k = 0; k < BK; ++k) {
      const float4 ra = *reinterpret_cast<const float4*>(&As[k][ty * 4]);
      const float4 rb = *reinterpret_cast<const float4*>(&Ws[k][tx * 4]);
      const float a[4] = {ra.x, ra.y, ra.z, ra.w};
      const float b[4] = {rb.x, rb.y, rb.z, rb.w};
#pragma unroll
      for (int i = 0; i < 4; ++i)
#pragma unroll
        for (int j = 0; j < 4; ++j) acc[i][j] += a[i] * b[j];
    }
    __syncthreads();
  }

  const float4 bv = *reinterpret_cast<const float4*>(&bias[col0 + tx * 4]);
#pragma unroll
  for (int i = 0; i < 4; ++i) {
    const int m = row0 + ty * 4 + i;
    float4 o;
    o.x = acc[i][0] + bv.x;
    o.y = acc[i][1] + bv.y;
    o.z = acc[i][2] + bv.z;
    o.w = acc[i][3] + bv.w;
    *reinterpret_cast<float4*>(&l_out[(size_t)m * NODE_DIM + col0 + tx * 4]) = o;
  }
}

// ---------------- Kernel 2: scores, grouped argmin, outputs ----------------
// Pinned across 3 structural variants at 85 us / 257 MB L2-miss / 3.1 TB/s:
// LLC random 64B-line delivery ceiling. Traffic-reduction alternatives
// (bf16 feats, edge-sort by neighbor, v-chunking) all compute to >= traffic
// or break argmin tie semantics — see R4 post-mortem.
__global__ __launch_bounds__(256) void sampler_kernel(
    const int* __restrict__ ids,
    const int* __restrict__ adj,
    const float* __restrict__ features,
    const float* __restrict__ l,
    float* __restrict__ out_sel,
    float* __restrict__ out_att,
    float* __restrict__ out_nz1,
    float* __restrict__ out_nz2) {
  __shared__ float l_s[NODE_DIM];
  __shared__ int   adj_s[MAX_DEG];
  __shared__ float nz_s[NSAMP];

  const int v   = blockIdx.x;
  const int tid = threadIdx.x;
  const int nid = ids[v];

  l_s[tid] = l[(size_t)v * NODE_DIM + tid];
  if (tid < MAX_DEG) adj_s[tid] = adj[(size_t)nid * MAX_DEG + tid];
  __syncthreads();

  const int wave = tid >> 6;       // 0..3
  const int lane = tid & 63;
  const int q    = lane >> 2;      // 0..15: neighbor slot within wave
  const int sub  = lane & 3;       // 0..3 : dim-chunk within quad
  const int k    = wave * 16 + q;  // neighbor index 0..63

  const int nb = adj_s[k];
  const float* __restrict__ rowp = features + (size_t)nb * NODE_DIM + sub * 4;
  const float* __restrict__ lp   = l_s + sub * 4;

  float p = 0.0f;
#pragma unroll
  for (int c = 0; c < 16; ++c) {
    const float4 f  = *reinterpret_cast<const float4*>(rowp + c * 16);
    const float4 lv = *reinterpret_cast<const float4*>(lp + c * 16);
    p += f.x * lv.x + f.y * lv.y + f.z * lv.z + f.w * lv.w;
  }
  p += __shfl_xor(p, 1, 64);
  p += __shfl_xor(p, 2, 64);
  float s = p > 0.0f ? p : 0.0f;   // relu

  int g = q & 3;
  {
    float os = __shfl_xor(s, 4, 64);
    int   og = __shfl_xor(g, 4, 64);
    if (os < s || (os == s && og < g)) { s = os; g = og; }
    os = __shfl_xor(s, 8, 64);
    og = __shfl_xor(g, 8, 64);
    if (os < s || (os == s && og < g)) { s = os; g = og; }
  }

  if ((lane & 15) == 0) {
    const int gl    = lane >> 4;
    const int s_idx = wave * 4 + gl;
    const int selid = adj_s[s_idx * GROUP_DIM + g];
    out_sel[(size_t)v * NSAMP + s_idx] = (float)selid;
    out_att[(size_t)v * NSAMP + s_idx] = 1.0f;
    nz_s[s_idx] = (selid == SENTINEL) ? 0.0f : 1.0f;
  }
  __syncthreads();

  if (tid == 0) {
    float nz = 0.0f;
#pragma unroll
    for (int t = 0; t < NSAMP; ++t) nz += nz_s[t];
    out_nz1[v] = nz;
    out_nz2[v] = nz;
  }
}

extern "C" void kernel_launch(void* const* d_in, const int* in_sizes, int n_in,
                              void* d_out, int out_size, void* d_ws,
                              size_t ws_size, hipStream_t stream) {
  const int*   ids      = (const int*)d_in[0];
  const int*   adj      = (const int*)d_in[1];
  const float* features = (const float*)d_in[2];
  const float* W        = (const float*)d_in[3];
  const float* bias     = (const float*)d_in[4];

  float* l_ws = (float*)d_ws;  // NUM_V * NODE_DIM floats = 8 MB

  float* out     = (float*)d_out;
  float* out_sel = out;
  float* out_att = out + (size_t)NUM_V * NSAMP;
  float* out_nz1 = out + (size_t)2 * NUM_V * NSAMP;
  float* out_nz2 = out_nz1 + NUM_V;

  gemm_l_kernel<<<dim3(NUM_V / BM, NODE_DIM / BN), 256, 0, stream>>>(
      ids, features, W, bias, l_ws);
  sampler_kernel<<<NUM_V, 256, 0, stream>>>(ids, adj, features, l_ws, out_sel,
                                            out_att, out_nz1, out_nz2);
}